// Round 9
// baseline (472.262 us; speedup 1.0000x reference)
//
#include <hip/hip_runtime.h>

typedef _Float16 half8_t __attribute__((ext_vector_type(8)));
typedef _Float16 half4_t __attribute__((ext_vector_type(4)));
typedef float floatx4 __attribute__((ext_vector_type(4)));
typedef float f32x16 __attribute__((ext_vector_type(16)));

// async global->LDS, 16B per lane. lds ptr wave-uniform; HW writes lane L at
// ldsbase + L*16.
__device__ inline void gload16(const void* g, void* l) {
  __builtin_amdgcn_global_load_lds(
      (const __attribute__((address_space(1))) unsigned int*)g,
      (__attribute__((address_space(3))) unsigned int*)l, 16, 0, 0);
}

// ==== 256x256 BT GEMM, 32x32x16 MFMA, 2-phase, ks-outer (indep chains) ====
// C[m,n] = sum_h A[m,h]*B[n,h] (+bias). K=1024 = 16 tiles of BK=64.
// 512 threads = 8 waves in 2(wr) x 4(wc); per-wave C slice 128x64
// (4 mi-rows of 32) x (2 ni-cols of 32) = 8 accumulators f32x16.
//
// LDS (128 KiB): per operand per parity 32 KB = 2048 x 16B chunks,
//   slot(m, kb) = m*8 + (kb ^ (m&7)), kb = k/8  [XOR involution both sides]
// Staging coalesced (r7): instr (wid,h,i) covers chunks c0..c0+63,
//   c0 = h*1024 + wid*128 + i*64; 8-lane groups read one aligned 128B row
//   segment; laneoff = (L>>3)*ld + ((L&7)^(L>>3))*8.
// Frag reads: row*128 + xk*16, xk[ks] = (ks*2+hi) ^ (lo&7).
//
// KEY CHANGE vs r7: the accumulate order. r0-r8 ran ks INNERMOST ->
// consecutive MFMAs hit the SAME accumulator -> in-order wave eats the
// MFMA latency-throughput gap on every instruction (MfmaUtil stuck ~27-33%
// across three different schedules). Now ks is OUTERMOST, mi inner: 4
// independent chains, dependency distance 4 (~128 cyc cover).
//
// Per K-tile t (p=t&1, q=p^1), 2 phases:
//  Ph1: read ALL frags from p (A 16 + B 8 ds_read_b128); stage B-h0(t+1)->q;
//       barrier; lgkmcnt(0); setprio1; 16 MFMA (ni=0, ks-outer); setprio0;
//       barrier.   [after lgkm(0)+barrier, ALL p slots are dead]
//  Ph2: stage A-h0,A-h1,B-h1 (t+2)->p; setprio1; 16 MFMA (ni=1, regs only);
//       setprio0; vmcnt(6); barrier.
// vmcnt(6) at Ph2 end: outstanding = Ph1(t)'s 2 + Ph2(t)'s 6; drains
// Ph2(t-1)'s 6 + Ph1(t)'s 2 = everything tile t+1 reads; keeps t+2's 6.
// Never 0 in the loop. Tail: clamped re-stages land dead-or-identical.
constexpr int NT = 16;  // K / 64

// all A frags: mi 0..3 -> row (mi>>1)*128 + wr*64 + (mi&1)*32 + lo
__device__ inline void lda_all(const char* sA, int wr, int lo, const int* xk,
                               half8_t af[4][4]) {
#pragma unroll
  for (int mi = 0; mi < 4; ++mi) {
    const int row = (mi >> 1) * 128 + wr * 64 + (mi & 1) * 32 + lo;
#pragma unroll
    for (int ks = 0; ks < 4; ++ks)
      af[mi][ks] = *(const half8_t*)(sA + (size_t)(row * 128 + xk[ks] * 16));
  }
}

// all B frags: ni 0..1 -> row ni*128 + wc*32 + lo
__device__ inline void ldb_all(const char* sB, int wc, int lo, const int* xk,
                               half8_t bf[2][4]) {
#pragma unroll
  for (int ni = 0; ni < 2; ++ni) {
    const int row = ni * 128 + wc * 32 + lo;
#pragma unroll
    for (int ks = 0; ks < 4; ++ks)
      bf[ni][ks] = *(const half8_t*)(sB + (size_t)(row * 128 + xk[ks] * 16));
  }
}

// one C column (ni): ks OUTER, mi inner -> 4 independent chains, distance 4
template <int NI>
__device__ inline void mfma_col(const half8_t af[4][4], const half8_t bf[2][4],
                                f32x16 acc[4][2]) {
  __builtin_amdgcn_s_setprio(1);
#pragma unroll
  for (int ks = 0; ks < 4; ++ks)
#pragma unroll
    for (int mi = 0; mi < 4; ++mi)
      acc[mi][NI] = __builtin_amdgcn_mfma_f32_32x32x16_f16(
          af[mi][ks], bf[NI][ks], acc[mi][NI], 0, 0, 0);
  __builtin_amdgcn_s_setprio(0);
}

// stage half h (rows [h*128,h*128+128)) of K-tile u of operand X (X already
// includes the block tile offset). laneoff = (L>>3)*ld + ((L&7)^(L>>3))*8.
__device__ inline void stage_half(const _Float16* __restrict__ X, long laneoff,
                                  int ldx, int u, char* opbase, int h,
                                  int wid) {
#pragma unroll
  for (int i = 0; i < 2; ++i) {
    const int c0 = h * 1024 + wid * 128 + i * 64;
    gload16(X + (long)(c0 >> 3) * ldx + u * 64 + laneoff,
            opbase + (size_t)c0 * 16);
  }
}

template <typename OT, int BIAS, int GX, int GY>
__global__ __launch_bounds__(512, 2) void gemm256(
    const _Float16* __restrict__ A, long As, int lda,
    const _Float16* __restrict__ B, long Bs, int ldb,
    OT* __restrict__ C, long Cs, int ldc, const float* __restrict__ bias,
    int biasStride) {
  __shared__ char smem[131072];  // A: p*32768, B: 65536 + p*32768

  // XCD chunk swizzle (grids are 256/512, always %8==0)
  const int id = blockIdx.x;
  const int chunk = gridDim.x >> 3;
  const int nid = (id & 7) * chunk + (id >> 3);
  const int bx = nid % GX;
  const int by = (nid / GX) % GY;
  const int bz = nid / (GX * GY);

  const int tid = threadIdx.x;
  const int lane = tid & 63;
  const int wid = tid >> 6;
  const int wr = wid >> 2;   // 0..1
  const int wc = wid & 3;    // 0..3
  const int lo = lane & 31;
  const int hi = lane >> 5;
  const int l7 = lane & 7;
  const int l8 = lane >> 3;
  const long laneA = (long)l8 * lda + ((l7 ^ l8) << 3);
  const long laneB = (long)l8 * ldb + ((l7 ^ l8) << 3);
  int xk[4];
#pragma unroll
  for (int ks = 0; ks < 4; ++ks) xk[ks] = (ks * 2 + hi) ^ l7;

  const long m0 = (long)by * 256;
  const long n0 = (long)bx * 256;
  const _Float16* Ab = A + (long)bz * As + m0 * (long)lda;
  const _Float16* Bb = B + (long)bz * Bs + n0 * (long)ldb;
  C += (long)bz * Cs;

  f32x16 acc[4][2] = {};
  half8_t af[4][4], bf[2][4];

  char* sA0 = smem;
  char* sA1 = smem + 32768;
  char* sB0 = smem + 65536;
  char* sB1 = smem + 65536 + 32768;

  // ---- prologue: t0 full -> par0 (8), t1 {A-h0,A-h1,B-h1} -> par1 (6)
  stage_half(Ab, laneA, lda, 0, sA0, 0, wid);
  stage_half(Ab, laneA, lda, 0, sA0, 1, wid);
  stage_half(Bb, laneB, ldb, 0, sB0, 0, wid);
  stage_half(Bb, laneB, ldb, 0, sB0, 1, wid);
  stage_half(Ab, laneA, lda, 1, sA1, 0, wid);
  stage_half(Ab, laneA, lda, 1, sA1, 1, wid);
  stage_half(Bb, laneB, ldb, 1, sB1, 1, wid);
  asm volatile("s_waitcnt vmcnt(6)" ::: "memory");  // drain t0, keep t1's 6
  __builtin_amdgcn_s_barrier();

  for (int t = 0; t < NT; ++t) {
    const int p = t & 1, q = p ^ 1;
    char* sAp = smem + p * 32768;
    char* sBp = smem + 65536 + p * 32768;
    char* sBq = smem + 65536 + q * 32768;
    const int u1 = (t + 1 < NT) ? t + 1 : NT - 1;
    const int u2 = (t + 2 < NT) ? t + 2 : NT - 1;

    // ---- Ph1: read everything from p; stage B-h0(t+1)->q; MFMA ni=0
    lda_all(sAp, wr, lo, xk, af);
    ldb_all(sBp, wc, lo, xk, bf);
    stage_half(Bb, laneB, ldb, u1, sBq, 0, wid);
    __builtin_amdgcn_s_barrier();
    asm volatile("s_waitcnt lgkmcnt(0)" ::: "memory");
    mfma_col<0>(af, bf, acc);
    __builtin_amdgcn_s_barrier();  // all waves done reading p

    // ---- Ph2: stage t+2 -> p (all slots dead); MFMA ni=1 (regs only)
    stage_half(Ab, laneA, lda, u2, sAp, 0, wid);
    stage_half(Ab, laneA, lda, u2, sAp, 1, wid);
    stage_half(Bb, laneB, ldb, u2, sBp, 1, wid);
    mfma_col<1>(af, bf, acc);
    asm volatile("s_waitcnt vmcnt(6)" ::: "memory");  // t+1 fully resident
    __builtin_amdgcn_s_barrier();
  }

  asm volatile("s_waitcnt vmcnt(0)" ::: "memory");

  // epilogue: 32x32 C/D layout col = lo, row = (e&3) + 8*(e>>2) + 4*hi
#pragma unroll
  for (int mi = 0; mi < 4; ++mi) {
    const int r0 = (mi >> 1) * 128 + wr * 64 + (mi & 1) * 32 + 4 * hi;
#pragma unroll
    for (int ni = 0; ni < 2; ++ni) {
      const int cc = (int)n0 + ni * 128 + wc * 32 + lo;
#pragma unroll
      for (int e = 0; e < 16; ++e) {
        const long row = m0 + r0 + (e & 3) + 8 * (e >> 2);
        float v = acc[mi][ni][e];
        if constexpr (BIAS == 1) v += bias[bz * biasStride + cc];
        if constexpr (BIAS == 2) v += bias[(int)row];
        C[row * (long)ldc + cc] = (OT)v;
      }
    }
  }
}

// ===================== auxiliary kernels =====================

// fp32 -> fp16, one float4 chunk per thread, 3 tensors of 16M floats each.
__global__ __launch_bounds__(256) void convert_x(const float* __restrict__ x0,
                                                 const float* __restrict__ x1,
                                                 const float* __restrict__ x2,
                                                 _Float16* __restrict__ out) {
  int i = blockIdx.x * 256 + threadIdx.x;  // 12582912 chunks total
  int t = i >> 22;                         // 4194304 chunks per tensor
  int j = i & 4194303;
  const float* src = (t == 0) ? x0 : (t == 1) ? x1 : x2;
  floatx4 v = ((const floatx4*)src)[j];
  half4_t h = {(_Float16)v[0], (_Float16)v[1], (_Float16)v[2], (_Float16)v[3]};
  ((half4_t*)out)[i] = h;
}

__global__ __launch_bounds__(256) void convert_w(const float* __restrict__ Wq,
                                                 const float* __restrict__ Wk,
                                                 const float* __restrict__ Wv,
                                                 _Float16* __restrict__ out) {
  int i = blockIdx.x * 256 + threadIdx.x;  // 786432 chunks total
  int t = i >> 18;                         // 262144 chunks per tensor
  int j = i & 262143;
  const float* src = (t == 0) ? Wq : (t == 1) ? Wk : Wv;
  floatx4 v = ((const floatx4*)src)[j];
  half4_t h = {(_Float16)v[0], (_Float16)v[1], (_Float16)v[2], (_Float16)v[3]};
  ((half4_t*)out)[i] = h;
}

__global__ __launch_bounds__(256) void pack_bias(const float* __restrict__ bq,
                                                 const float* __restrict__ bk,
                                                 const float* __restrict__ bv,
                                                 float* __restrict__ out) {
  int b = blockIdx.x;
  const float* src = (b == 0) ? bq : (b == 1) ? bk : bv;
  ((floatx4*)out)[b * 256 + threadIdx.x] =
      ((const floatx4*)src)[threadIdx.x];
}

// Row softmax over 1024 fp16 scores, fp32 math, fp16 result in place.
__global__ __launch_bounds__(256) void softmax_rows_h(_Float16* __restrict__ S) {
  long row = blockIdx.x;
  _Float16* Sr = S + row * 1024;
  int tid = threadIdx.x, lane = tid & 63, wid = tid >> 6;
  half4_t x = ((const half4_t*)Sr)[tid];
  float x0 = x[0], x1 = x[1], x2 = x[2], x3 = x[3];
  float mx = fmaxf(fmaxf(x0, x1), fmaxf(x2, x3));
#pragma unroll
  for (int off = 32; off > 0; off >>= 1) mx = fmaxf(mx, __shfl_xor(mx, off));
  __shared__ float redm[4];
  if (lane == 0) redm[wid] = mx;
  __syncthreads();
  mx = fmaxf(fmaxf(redm[0], redm[1]), fmaxf(redm[2], redm[3]));
  float e0 = __expf(x0 - mx), e1 = __expf(x1 - mx);
  float e2 = __expf(x2 - mx), e3 = __expf(x3 - mx);
  float s = e0 + e1 + e2 + e3;
#pragma unroll
  for (int off = 32; off > 0; off >>= 1) s += __shfl_xor(s, off);
  __shared__ float reds[4];
  if (lane == 0) reds[wid] = s;
  __syncthreads();
  s = reds[0] + reds[1] + reds[2] + reds[3];
  float inv = 1.0f / s;
  half4_t h = {(_Float16)(e0 * inv), (_Float16)(e1 * inv),
               (_Float16)(e2 * inv), (_Float16)(e3 * inv)};
  ((half4_t*)Sr)[tid] = h;
}

extern "C" void kernel_launch(void* const* d_in, const int* in_sizes, int n_in,
                              void* d_out, int out_size, void* d_ws,
                              size_t ws_size, hipStream_t stream) {
  (void)in_sizes; (void)n_in; (void)out_size; (void)ws_size;
  const float* meme  = (const float*)d_in[0];
  const float* text  = (const float*)d_in[1];
  const float* emoji = (const float*)d_in[2];
  const float* Wq = (const float*)d_in[3];
  const float* bq = (const float*)d_in[4];
  const float* Wk = (const float*)d_in[5];
  const float* bk = (const float*)d_in[6];
  const float* Wv = (const float*)d_in[7];
  const float* bv = (const float*)d_in[8];

  const long MB = 1024 * 1024;
  char* ws = (char*)d_ws;
  // [0,6) MB:    hWq/hWk/hWv fp16 (contiguous, stride 1M halves)
  // [6,7):       packed bias 3*1024 fp32
  // [7,39) MB:   meme_h  -> dead after QK GEMM -> reused as S (fp16, 32MB)
  // [39,71) MB:  text_h  -> dead after QK GEMM -> reused as Vt (fp16, 32MB)
  // [71,103) MB: emoji_h -> dead after Vt GEMM
  // [103,135):   Qh fp16   [135,167): Kh fp16
  _Float16* hWq = (_Float16*)ws;
  float* pbias  = (float*)(ws + 6 * MB);
  _Float16* mh  = (_Float16*)(ws + 7 * MB);
  _Float16* th  = (_Float16*)(ws + 39 * MB);
  _Float16* eh  = (_Float16*)(ws + 71 * MB);
  _Float16* Qh  = (_Float16*)(ws + 103 * MB);
  _Float16* Kh  = (_Float16*)(ws + 135 * MB);
  _Float16* S   = mh;  // aliases meme_h (dead by then)
  _Float16* Vt  = th;  // aliases text_h (dead by then)
  _Float16* hWv = hWq + 2 * MB;

  dim3 blk(256), blk5(512);
  convert_w<<<3072, blk, 0, stream>>>(Wq, Wk, Wv, hWq);
  pack_bias<<<3, blk, 0, stream>>>(bq, bk, bv, pbias);
  convert_x<<<49152, blk, 0, stream>>>(meme, text, emoji, mh);

  // Q,K projections batched (z=2, contiguous workspace): M=16384, N=1024.
  gemm256<_Float16, 1, 4, 64><<<dim3(512), blk5, 0, stream>>>(
      mh, 16777216, 1024, hWq, 1048576, 1024, Qh, 16777216, 1024, pbias, 1024);
  // Vt[a, b*L+l] = sum_h Wv[a,h]*emoji[b,l,h] + bv[a]  (V transposed)
  gemm256<_Float16, 2, 64, 4><<<dim3(256), blk5, 0, stream>>>(
      hWv, 0, 1024, eh, 0, 1024, Vt, 0, 16384, pbias + 2048, 0);
  // S[b] = Q[b] @ K[b]^T -> fp16. per-batch 1024x1024, z=16.
  gemm256<_Float16, 0, 4, 4><<<dim3(256), blk5, 0, stream>>>(
      Qh, 1048576, 1024, Kh, 1048576, 1024, S, 1048576, 1024, nullptr, 0);
  // softmax rows, fp16 in place
  softmax_rows_h<<<16384, blk, 0, stream>>>(S);
  // O[b] = P[b] @ V[b] via Vt: C[q,a] = sum_k P[q,k] * Vt[a, b*1024+k]
  gemm256<float, 0, 4, 4><<<dim3(256), blk5, 0, stream>>>(
      S, 1048576, 1024, Vt, 1024, 16384, (float*)d_out, 1048576, 1024,
      nullptr, 0);
}